// Round 10
// baseline (87.938 us; speedup 1.0000x reference)
//
#include <hip/hip_runtime.h>
#include <hip/hip_bf16.h>

typedef __bf16 bf8 __attribute__((ext_vector_type(8)));
typedef float f32x4 __attribute__((ext_vector_type(4)));

#define NF 160
#define NC 10
// w = exp(-d/1.1) = exp2(-sqrt(C2 * d^2)), C2 = (log2e/1.1)^2
#define WSCALE (-1.4426950408889634f / 1.1f)
#define C2SCALE (WSCALE * WSCALE)
#define NEG2C2 (-2.0f * C2SCALE)

// Unified packed tile: 32 addr rows, 12288 B (fragment-ordered for direct
// global->MFMA consumption; all offsets in bf16 elements):
//   [   0,5120): K frags  [half(2)][kk(5)][lane(64)][8 bf16]
//   [5120,5632): M frags  [lane(64)][8 bf16]   (PV A-operand, ones col 10)
//   [5632,5696): y2*C2    f32[32]
//   [5696,6144): zero pad
#define TILE_E 6144   // bf16 elements
#define TILE_B 12288  // bytes

// ===========================================================================
// PRE-PASS: build unified tiles (verified layout, rounds 7-9).
// ===========================================================================
__global__ __launch_bounds__(256)
void pack_kernel(const float* __restrict__ addr, const float* __restrict__ Mm,
                 __bf16* __restrict__ pk, int A)
{
    const int nkb = A / 64;
    const int lane = threadIdx.x & 63;
    const int w    = threadIdx.x >> 6;
    const int l15  = lane & 15;
    const int g    = lane >> 4;

    if ((int)blockIdx.x < nkb) {
        const int b = blockIdx.x * 4 + w;       // 16-row block
        const int p = b >> 1, h = b & 1;        // tile, half
        const float* row = addr + (size_t)(b * 16 + l15) * NF;
        __bf16* dst = pk + (size_t)p * TILE_E + h * 2560;
        float ss = 0.f;
        #pragma unroll
        for (int kk = 0; kk < 5; ++kk) {
            float4 lo = *(const float4*)(row + 32 * kk + 4 * g);
            float4 hi = *(const float4*)(row + 32 * kk + 4 * g + 16);
            ss += lo.x*lo.x + lo.y*lo.y + lo.z*lo.z + lo.w*lo.w
                + hi.x*hi.x + hi.y*hi.y + hi.z*hi.z + hi.w*hi.w;
            bf8 f;
            f[0]=(__bf16)lo.x; f[1]=(__bf16)lo.y; f[2]=(__bf16)lo.z; f[3]=(__bf16)lo.w;
            f[4]=(__bf16)hi.x; f[5]=(__bf16)hi.y; f[6]=(__bf16)hi.z; f[7]=(__bf16)hi.w;
            *(bf8*)(dst + kk * 512 + lane * 8) = f;
        }
        ss += __shfl_xor(ss, 16, 64);
        ss += __shfl_xor(ss, 32, 64);
        if (g == 0)
            ((float*)(pk + (size_t)p * TILE_E + 5632))[h * 16 + l15] = ss * C2SCALE;
    } else {
        const int mb = (blockIdx.x - nkb) * 4 + w;   // tile index (32 rows)
        bf8 f;
        #pragma unroll
        for (int e = 0; e < 8; ++e) {
            int r = mb * 32 + 4 * g + (e & 3) + 16 * (e >> 2);
            float v = (l15 < NC) ? Mm[(size_t)r * NC + l15] : (l15 == NC ? 1.0f : 0.0f);
            f[e] = (__bf16)v;
        }
        *(bf8*)(pk + (size_t)mb * TILE_E + 5120 + lane * 8) = f;
        if (lane < 56) {                              // zero pad 896 B
            uint4 z = {0u, 0u, 0u, 0u};
            *(uint4*)(pk + (size_t)mb * TILE_E + 5696 + lane * 8) = z;
        }
    }
}

// ===========================================================================
// MAIN: NO LDS, NO barriers. Fragments are read directly from the packed
// global buffer (L1/L2-resident: per-split chunk ~200 KB, XCD-pinned, and all
// 4 waves of a block read identical addresses -> L1 broadcast). Tile loop is
// pure {load -> MFMA -> trans -> PV} with affine addresses; occupancy is
// VGPR-bound only. Grid (N/128)*S, S=64 -> 2048 blocks = 8/CU.
// ===========================================================================
__global__ void fused_fast(const float* __restrict__ inp,
                           const __bf16* __restrict__ pk,
                           float* __restrict__ part,
                           int N, int S, int ntt)
{
    const int bid   = blockIdx.x;
    const int split = bid % S;     // S mult of 8 -> split's chunk pinned to one XCD
    const int qblk  = bid / S;
    const int t     = threadIdx.x;
    const int lane  = t & 63;
    const int wave  = t >> 6;
    const int l15   = lane & 15;
    const int g     = lane >> 4;

    // ---- hoist Q fragments + x2*C2 (per wave's own 32 queries)
    const int qbase = qblk * 128 + wave * 32;
    bf8 qfrag[2][5];
    float x2q[2];
    #pragma unroll
    for (int qf = 0; qf < 2; ++qf) {
        const float* qrow = inp + (size_t)(qbase + qf * 16 + l15) * NF;
        float ss = 0.f;
        #pragma unroll
        for (int kk = 0; kk < 5; ++kk) {
            float4 lo = *(const float4*)(qrow + 32 * kk + 4 * g);
            float4 hi = *(const float4*)(qrow + 32 * kk + 4 * g + 16);
            ss += lo.x*lo.x + lo.y*lo.y + lo.z*lo.z + lo.w*lo.w
                + hi.x*hi.x + hi.y*hi.y + hi.z*hi.z + hi.w*hi.w;
            bf8 f;
            f[0]=(__bf16)lo.x; f[1]=(__bf16)lo.y; f[2]=(__bf16)lo.z; f[3]=(__bf16)lo.w;
            f[4]=(__bf16)hi.x; f[5]=(__bf16)hi.y; f[6]=(__bf16)hi.z; f[7]=(__bf16)hi.w;
            qfrag[qf][kk] = f;
        }
        ss += __shfl_xor(ss, 16, 64);
        ss += __shfl_xor(ss, 32, 64);
        x2q[qf] = ss * C2SCALE;
    }

    f32x4 acc[2];
    acc[0] = (f32x4){0.f,0.f,0.f,0.f};
    acc[1] = (f32x4){0.f,0.f,0.f,0.f};

    const int ts = (split * ntt) / S;
    const int nt = ((split + 1) * ntt) / S - ts;
    const __bf16* src = pk + (size_t)ts * TILE_E;

    for (int k = 0; k < nt; ++k) {
        const __bf16* kb = src + (size_t)k * TILE_E;

        // fragment + y2 loads, straight from global (L1/L2-hit, coalesced 16B)
        bf8 mf = *(const bf8*)(kb + 5120 + lane * 8);
        float y2r[8];
        {
            const float* y2p = (const float*)(kb + 5632);
            #pragma unroll
            for (int m = 0; m < 2; ++m) {
                f32x4 yv = *(const f32x4*)(y2p + m * 16 + 4 * g);
                y2r[m*4+0] = yv[0]; y2r[m*4+1] = yv[1];
                y2r[m*4+2] = yv[2]; y2r[m*4+3] = yv[3];
            }
        }
        bf8 kf[2][5];
        #pragma unroll
        for (int m = 0; m < 2; ++m)
            #pragma unroll
            for (int kk = 0; kk < 5; ++kk)
                kf[m][kk] = *(const bf8*)(kb + m * 2560 + kk * 512 + lane * 8);

        // ---- QK^T: 4 interleaved MFMA chains
        __builtin_amdgcn_s_setprio(1);
        f32x4 s00 = {0.f,0.f,0.f,0.f}, s01 = {0.f,0.f,0.f,0.f};
        f32x4 s10 = {0.f,0.f,0.f,0.f}, s11 = {0.f,0.f,0.f,0.f};
        #pragma unroll
        for (int kk = 0; kk < 5; ++kk) {
            s00 = __builtin_amdgcn_mfma_f32_16x16x32_bf16(kf[0][kk], qfrag[0][kk], s00, 0,0,0);
            s01 = __builtin_amdgcn_mfma_f32_16x16x32_bf16(kf[1][kk], qfrag[0][kk], s01, 0,0,0);
            s10 = __builtin_amdgcn_mfma_f32_16x16x32_bf16(kf[0][kk], qfrag[1][kk], s10, 0,0,0);
            s11 = __builtin_amdgcn_mfma_f32_16x16x32_bf16(kf[1][kk], qfrag[1][kk], s11, 0,0,0);
        }
        __builtin_amdgcn_s_setprio(0);

        // ---- dist -> weight -> PV
        bf8 p0, p1;
        #pragma unroll
        for (int r = 0; r < 4; ++r) {
            float d2a = fmaf(s00[r], NEG2C2, x2q[0] + y2r[r]);
            float d2b = fmaf(s01[r], NEG2C2, x2q[0] + y2r[4 + r]);
            p0[r]     = (__bf16)__builtin_amdgcn_exp2f(-__builtin_amdgcn_sqrtf(d2a));
            p0[4 + r] = (__bf16)__builtin_amdgcn_exp2f(-__builtin_amdgcn_sqrtf(d2b));
            float d2c = fmaf(s10[r], NEG2C2, x2q[1] + y2r[r]);
            float d2d = fmaf(s11[r], NEG2C2, x2q[1] + y2r[4 + r]);
            p1[r]     = (__bf16)__builtin_amdgcn_exp2f(-__builtin_amdgcn_sqrtf(d2c));
            p1[4 + r] = (__bf16)__builtin_amdgcn_exp2f(-__builtin_amdgcn_sqrtf(d2d));
        }
        acc[0] = __builtin_amdgcn_mfma_f32_16x16x32_bf16(mf, p0, acc[0], 0,0,0);
        acc[1] = __builtin_amdgcn_mfma_f32_16x16x32_bf16(mf, p1, acc[1], 0,0,0);
    }

    // ---- epilogue: partials [S][N][12] (cols 0..9 = num, col 10 = denom)
    #pragma unroll
    for (int qf = 0; qf < 2; ++qf) {
        if (g < 3) {
            const int q = qbase + qf * 16 + l15;
            *(f32x4*)(part + ((size_t)split * N + q) * 12 + 4 * g) = acc[qf];
        }
    }
}

// 4 threads per query, shfl-reduce, lane0-of-4 writes.
__global__ void combine_kernel(const float* __restrict__ ws, float* __restrict__ out,
                               int N, int nsplit)
{
    int gid = blockIdx.x * blockDim.x + threadIdx.x;
    int q = gid >> 2, part = gid & 3;
    if (q >= N) return;
    f32x4 n0 = {0.f,0.f,0.f,0.f}, n1 = {0.f,0.f,0.f,0.f}, n2 = {0.f,0.f,0.f,0.f};
    for (int s = part; s < nsplit; s += 4) {
        const float* p = ws + ((size_t)s * N + q) * 12;
        n0 += *(const f32x4*)(p);
        n1 += *(const f32x4*)(p + 4);
        n2 += *(const f32x4*)(p + 8);
    }
    #pragma unroll
    for (int d = 1; d < 4; d <<= 1) {
        #pragma unroll
        for (int i = 0; i < 4; ++i) {
            n0[i] += __shfl_xor(n0[i], d, 64);
            n1[i] += __shfl_xor(n1[i], d, 64);
            n2[i] += __shfl_xor(n2[i], d, 64);
        }
    }
    if (part == 0) {
        float inv = 1.f / n2[2];
        float o[NC] = {n0[0],n0[1],n0[2],n0[3],n1[0],n1[1],n1[2],n1[3],n2[0],n2[1]};
        #pragma unroll
        for (int c = 0; c < NC; ++c) out[(size_t)q * NC + c] = o[c] * inv;
    }
}

// ===========================================================================
// FALLBACK (round-1 kernel): used only if ws too small for the packed path.
// ===========================================================================
#define QB 64
#define KVB 128
#define KPAD 164
#define MPAD 18

__global__ __launch_bounds__(256, 2)
void fused_dist_softmin(const float* __restrict__ inp,
                        const float* __restrict__ addr,
                        const float* __restrict__ Mm,
                        float* __restrict__ ws,
                        float* __restrict__ outp,
                        int N, int nsplit, int a_per_split, int direct)
{
    __shared__ __align__(16) __bf16 Klds[KVB][KPAD];
    __shared__ __align__(16) __bf16 Mlds[KVB][MPAD];
    __shared__ float y2lds[KVB];
    __shared__ float x2lds[QB];
    __shared__ float redbuf[4][4][16][16];

    const int bid = blockIdx.x;
    int split, qblock;
    if (nsplit == 8) { split = bid & 7; qblock = bid >> 3; }
    else             { split = bid % nsplit; qblock = bid / nsplit; }

    const int t    = threadIdx.x;
    const int lane = t & 63;
    const int wave = t >> 6;
    const int l15  = lane & 15;
    const int g    = lane >> 4;
    const int foff = 4 * g;

    if (t < QB) {
        const float* row = inp + (size_t)(qblock * QB + t) * NF;
        float s = 0.f;
        #pragma unroll
        for (int i = 0; i < NF/4; ++i) {
            float4 v = *(const float4*)(row + 4*i);
            s += v.x*v.x + v.y*v.y + v.z*v.z + v.w*v.w;
        }
        x2lds[t] = s;
    }

    bf8 qfrag[4][5];
    #pragma unroll
    for (int qf = 0; qf < 4; ++qf) {
        const float* qrow = inp + (size_t)(qblock*QB + qf*16 + l15) * NF;
        #pragma unroll
        for (int kk = 0; kk < 5; ++kk) {
            float4 lo = *(const float4*)(qrow + 32*kk + foff);
            float4 hi = *(const float4*)(qrow + 32*kk + foff + 16);
            bf8 f;
            f[0]=(__bf16)lo.x; f[1]=(__bf16)lo.y; f[2]=(__bf16)lo.z; f[3]=(__bf16)lo.w;
            f[4]=(__bf16)hi.x; f[5]=(__bf16)hi.y; f[6]=(__bf16)hi.z; f[7]=(__bf16)hi.w;
            qfrag[qf][kk] = f;
        }
    }

    __syncthreads();
    float x2q[4];
    #pragma unroll
    for (int qf = 0; qf < 4; ++qf) x2q[qf] = x2lds[qf*16 + l15];

    f32x4 acc[4];
    #pragma unroll
    for (int qf = 0; qf < 4; ++qf) acc[qf] = (f32x4){0.f,0.f,0.f,0.f};

    const int wa      = wave * 32;
    const int a_begin = split * a_per_split;
    const int ntiles  = a_per_split / KVB;

    for (int tile = 0; tile < ntiles; ++tile) {
        const int a0 = a_begin + tile * KVB;
        __syncthreads();
        {
            const int r = t >> 1, h = t & 1;
            const float* rowp = addr + (size_t)(a0 + r) * NF + h*80;
            float ss = 0.f;
            #pragma unroll
            for (int i = 0; i < 20; ++i) {
                float4 v = *(const float4*)(rowp + 4*i);
                ss += v.x*v.x + v.y*v.y + v.z*v.z + v.w*v.w;
                union { __bf16 b[4]; uint2 u; } pk2;
                pk2.b[0]=(__bf16)v.x; pk2.b[1]=(__bf16)v.y;
                pk2.b[2]=(__bf16)v.z; pk2.b[3]=(__bf16)v.w;
                *(uint2*)&Klds[r][h*80 + 4*i] = pk2.u;
            }
            ss += __shfl_xor(ss, 1, 64);
            if (h == 0) y2lds[r] = ss;
        }
        for (int j = t; j < KVB*NC; j += 256) {
            int r = j / NC, c = j % NC;
            Mlds[r][c] = (__bf16)Mm[(size_t)(a0 + r)*NC + c];
        }
        for (int j = t; j < KVB*8; j += 256) {
            int r = j >> 3, c = 10 + (j & 7);
            Mlds[r][c] = (c == 10) ? (__bf16)1.0f : (__bf16)0.0f;
        }
        __syncthreads();

        bf8 kfrag[2][5];
        #pragma unroll
        for (int m = 0; m < 2; ++m) {
            const __bf16* krow = &Klds[wa + 16*m + l15][0];
            #pragma unroll
            for (int kk = 0; kk < 5; ++kk) {
                uint2 lo = *(const uint2*)(krow + 32*kk + foff);
                uint2 hi = *(const uint2*)(krow + 32*kk + foff + 16);
                union { unsigned int u[4]; bf8 v; } fr;
                fr.u[0]=lo.x; fr.u[1]=lo.y; fr.u[2]=hi.x; fr.u[3]=hi.y;
                kfrag[m][kk] = fr.v;
            }
        }
        float y2r[8];
        #pragma unroll
        for (int m = 0; m < 2; ++m)
            #pragma unroll
            for (int r = 0; r < 4; ++r)
                y2r[m*4 + r] = y2lds[wa + 16*m + 4*g + r];

        bf8 mfrag;
        #pragma unroll
        for (int e = 0; e < 8; ++e)
            mfrag[e] = Mlds[wa + 4*g + (e & 3) + 16*(e >> 2)][l15];

        #pragma unroll
        for (int qf = 0; qf < 4; ++qf) {
            f32x4 s0 = {0.f,0.f,0.f,0.f}, s1 = {0.f,0.f,0.f,0.f};
            #pragma unroll
            for (int kk = 0; kk < 5; ++kk) {
                s0 = __builtin_amdgcn_mfma_f32_16x16x32_bf16(kfrag[0][kk], qfrag[qf][kk], s0, 0, 0, 0);
                s1 = __builtin_amdgcn_mfma_f32_16x16x32_bf16(kfrag[1][kk], qfrag[qf][kk], s1, 0, 0, 0);
            }
            bf8 p;
            const float xq = x2q[qf];
            #pragma unroll
            for (int r = 0; r < 4; ++r) {
                float d2a = xq + y2r[r]     - 2.f*s0[r];
                float d2b = xq + y2r[4 + r] - 2.f*s1[r];
                float da = __builtin_amdgcn_sqrtf(d2a);
                float db = __builtin_amdgcn_sqrtf(d2b);
                p[r]     = (__bf16)__builtin_amdgcn_exp2f(da * WSCALE);
                p[4 + r] = (__bf16)__builtin_amdgcn_exp2f(db * WSCALE);
            }
            acc[qf] = __builtin_amdgcn_mfma_f32_16x16x32_bf16(mfrag, p, acc[qf], 0, 0, 0);
        }
    }

    #pragma unroll
    for (int qf = 0; qf < 4; ++qf)
        #pragma unroll
        for (int r = 0; r < 4; ++r)
            redbuf[wave][qf][4*g + r][l15] = acc[qf][r];
    __syncthreads();

    const int qf2 = t >> 6;
    const int qq  = (t >> 2) & 15;
    const int cg  = t & 3;
    float v[4];
    #pragma unroll
    for (int i = 0; i < 4; ++i) {
        const int c = cg*4 + i;
        v[i] = redbuf[0][qf2][c][qq] + redbuf[1][qf2][c][qq]
             + redbuf[2][qf2][c][qq] + redbuf[3][qf2][c][qq];
    }
    const int qg = qblock*QB + qf2*16 + qq;
    if (!direct) {
        float4 o; o.x=v[0]; o.y=v[1]; o.z=v[2]; o.w=v[3];
        *(float4*)(ws + ((size_t)split * N + qg) * 16 + cg*4) = o;
    } else {
        float den = redbuf[0][qf2][10][qq] + redbuf[1][qf2][10][qq]
                  + redbuf[2][qf2][10][qq] + redbuf[3][qf2][10][qq];
        float inv = 1.f / den;
        #pragma unroll
        for (int i = 0; i < 4; ++i) {
            int c = cg*4 + i;
            if (c < NC) outp[(size_t)qg * NC + c] = v[i] * inv;
        }
    }
}

__global__ void combine16_kernel(const float* __restrict__ ws, float* __restrict__ out,
                                 int N, int nsplit)
{
    int q = blockIdx.x * blockDim.x + threadIdx.x;
    if (q >= N) return;
    float num[NC];
    #pragma unroll
    for (int c = 0; c < NC; ++c) num[c] = 0.f;
    float den = 0.f;
    for (int s = 0; s < nsplit; ++s) {
        const float* p = ws + ((size_t)s * N + q) * 16;
        #pragma unroll
        for (int c = 0; c < NC; ++c) num[c] += p[c];
        den += p[10];
    }
    float inv = 1.f / den;
    #pragma unroll
    for (int c = 0; c < NC; ++c) out[(size_t)q * NC + c] = num[c] * inv;
}

// ===========================================================================
extern "C" void kernel_launch(void* const* d_in, const int* in_sizes, int n_in,
                              void* d_out, int out_size, void* d_ws, size_t ws_size,
                              hipStream_t stream)
{
    const float* inp  = (const float*)d_in[0];
    const float* addr = (const float*)d_in[1];
    const float* Mm   = (const float*)d_in[2];
    float* out = (float*)d_out;

    const int N = in_sizes[0] / NF;   // 4096
    const int A = in_sizes[1] / NF;   // 32768

    const size_t packed = (size_t)(A / 32) * TILE_B;

    int S = 0;
    const int cand[4] = {64, 32, 16, 8};
    for (int i = 0; i < 4; ++i) {
        int s = cand[i];
        if (packed + (size_t)s * N * 48 <= ws_size) { S = s; break; }
    }

    if (S && (N % 128) == 0 && (A % 128) == 0) {
        char* wsb = (char*)d_ws;
        __bf16* pk  = (__bf16*)wsb;
        float*  prt = (float*)(wsb + packed);

        const int nkb = A / 64, nmb = A / 128;
        pack_kernel<<<dim3(nkb + nmb), 256, 0, stream>>>(addr, Mm, pk, A);

        const int ntt = A / 32;
        fused_fast<<<dim3((N / 128) * S), 256, 0, stream>>>(inp, pk, prt, N, S, ntt);
        combine_kernel<<<dim3((N * 4 + 255) / 256), 256, 0, stream>>>(prt, out, N, S);
    } else {
        float* ws = (float*)d_ws;
        int nsplit = 1;
        for (int s = 8; s >= 2; s >>= 1) {
            if ((size_t)s * N * 16 * sizeof(float) <= ws_size && (A % (s * KVB)) == 0) {
                nsplit = s; break;
            }
        }
        const int direct = (nsplit == 1);
        const int a_per_split = A / nsplit;
        dim3 grid((N / QB) * nsplit);
        fused_dist_softmin<<<grid, 256, 0, stream>>>(inp, addr, Mm, ws, out,
                                                     N, nsplit, a_per_split, direct);
        if (!direct)
            combine16_kernel<<<dim3((N + 255) / 256), 256, 0, stream>>>(ws, out, N, nsplit);
    }
}

// Round 11
// 74.197 us; speedup vs baseline: 1.1852x; 1.1852x over previous
//
#include <hip/hip_runtime.h>
#include <hip/hip_bf16.h>

typedef __bf16 bf8 __attribute__((ext_vector_type(8)));
typedef float f32x4 __attribute__((ext_vector_type(4)));

#define NF 160
#define NC 10
// w = exp(-d/1.1) = exp2(-sqrt(C2*d^2)); C2 = (log2e/1.1)^2.
// QK^T MFMA computes C2*d^2 directly: K feats scaled by -SQ, Q feats by +SQ
// (SQ = sqrt(2*C2)), plus 4 ext features carrying x2*C2, y2*C2 (hi/lo split).
#define WSCALE (1.4426950408889634f / 1.1f)
#define C2SCALE (WSCALE * WSCALE)
#define SQSCALE 1.85483319237f   // sqrt(2*C2)

#define KKN 6                    // feature chunks of 32 (160 data + 4 ext + pad)
// Unified packed tile: 32 addr rows, 13312 B:
//   [    0, 6144): K frags [half(2)][kk(6)][lane(64)][8 bf16]
//   [ 6144, 6656): M frags [lane(64)][8 bf16] (PV A-operand, ones col 10)
#define TILE_E 6656   // bf16 elements
#define TILE_B 13312  // bytes

// ---------------------------------------------------------------------------
__device__ __forceinline__ void gload_lds16(const __bf16* gsrc, __bf16* ldst) {
    __builtin_amdgcn_global_load_lds(
        (const __attribute__((address_space(1))) unsigned int*)gsrc,
        (__attribute__((address_space(3))) unsigned int*)ldst,
        16, 0, 0);
}

// 832 x 16B per tile: 3 full rounds + 1 round on lanes 0..15 of each wave.
// Every wave issues exactly 4 gload_lds instructions -> uniform vmcnt.
__device__ __forceinline__ void stage4(const __bf16* src, __bf16* dst,
                                       int t, int wave, int lane) {
    gload_lds16(src + (size_t)t * 8,          dst + (size_t)t * 8);
    gload_lds16(src + ((size_t)256 + t) * 8,  dst + ((size_t)256 + t) * 8);
    gload_lds16(src + ((size_t)512 + t) * 8,  dst + ((size_t)512 + t) * 8);
    if (lane < 16) {
        const size_t o = (size_t)768 + wave * 16 + lane;
        gload_lds16(src + o * 8, dst + o * 8);
    }
}

// ===========================================================================
// PRE-PASS: K frags scaled by -SQ + ext chunk [y2hi,y2lo,1,1]; M frags.
// ===========================================================================
__global__ __launch_bounds__(256)
void pack_kernel(const float* __restrict__ addr, const float* __restrict__ Mm,
                 __bf16* __restrict__ pk, int A)
{
    const int nkb = A / 64;
    const int lane = threadIdx.x & 63;
    const int w    = threadIdx.x >> 6;
    const int l15  = lane & 15;
    const int g    = lane >> 4;

    if ((int)blockIdx.x < nkb) {
        const int b = blockIdx.x * 4 + w;       // 16-row block
        const int p = b >> 1, h = b & 1;        // tile, half
        const float* row = addr + (size_t)(b * 16 + l15) * NF;
        __bf16* dst = pk + (size_t)p * TILE_E + h * (KKN * 512);
        float ss = 0.f;
        #pragma unroll
        for (int kk = 0; kk < 5; ++kk) {
            float4 lo = *(const float4*)(row + 32 * kk + 4 * g);
            float4 hi = *(const float4*)(row + 32 * kk + 4 * g + 16);
            ss += lo.x*lo.x + lo.y*lo.y + lo.z*lo.z + lo.w*lo.w
                + hi.x*hi.x + hi.y*hi.y + hi.z*hi.z + hi.w*hi.w;
            bf8 f;
            f[0]=(__bf16)(-SQSCALE*lo.x); f[1]=(__bf16)(-SQSCALE*lo.y);
            f[2]=(__bf16)(-SQSCALE*lo.z); f[3]=(__bf16)(-SQSCALE*lo.w);
            f[4]=(__bf16)(-SQSCALE*hi.x); f[5]=(__bf16)(-SQSCALE*hi.y);
            f[6]=(__bf16)(-SQSCALE*hi.z); f[7]=(__bf16)(-SQSCALE*hi.w);
            *(bf8*)(dst + kk * 512 + lane * 8) = f;
        }
        ss += __shfl_xor(ss, 16, 64);
        ss += __shfl_xor(ss, 32, 64);
        const float y2C  = ss * C2SCALE;
        const float y2hi = (float)(__bf16)y2C;
        const float y2lo = y2C - y2hi;
        bf8 z = {(__bf16)0.f,(__bf16)0.f,(__bf16)0.f,(__bf16)0.f,
                 (__bf16)0.f,(__bf16)0.f,(__bf16)0.f,(__bf16)0.f};
        if (g == 0) { z[0] = (__bf16)y2hi; z[1] = (__bf16)y2lo;
                      z[2] = (__bf16)1.0f; z[3] = (__bf16)1.0f; }
        *(bf8*)(dst + 5 * 512 + lane * 8) = z;
    } else {
        const int mb = (blockIdx.x - nkb) * 4 + w;   // tile index (32 rows)
        bf8 f;
        #pragma unroll
        for (int e = 0; e < 8; ++e) {
            int r = mb * 32 + 4 * g + (e & 3) + 16 * (e >> 2);
            float v = (l15 < NC) ? Mm[(size_t)r * NC + l15] : (l15 == NC ? 1.0f : 0.0f);
            f[e] = (__bf16)v;
        }
        *(bf8*)(pk + (size_t)mb * TILE_E + 6144 + lane * 8) = f;
    }
}

// ===========================================================================
// MAIN: R9 pipeline (3 LDS buffers, counted vmcnt(4), one bare barrier/tile).
// QK^T MFMA now yields C2*d^2 directly; trans block is pure exp2(-sqrt(s)).
// ===========================================================================
__global__ void fused_fast(const float* __restrict__ inp,
                           const __bf16* __restrict__ pk,
                           float* __restrict__ part,
                           int N, int S, int ntt)
{
    __shared__ __align__(16) __bf16 kbuf[3][TILE_E];   // 39,936 B

    const int bid   = blockIdx.x;
    const int split = bid % S;
    const int qblk  = bid / S;
    const int t     = threadIdx.x;
    const int lane  = t & 63;
    const int wave  = t >> 6;
    const int l15   = lane & 15;
    const int g     = lane >> 4;

    // ---- hoist Q fragments (scaled by +SQ) + ext chunk (per wave: 32 queries)
    const int qbase = qblk * 128 + wave * 32;
    bf8 qfrag[2][KKN];
    #pragma unroll
    for (int qf = 0; qf < 2; ++qf) {
        const float* qrow = inp + (size_t)(qbase + qf * 16 + l15) * NF;
        float ss = 0.f;
        #pragma unroll
        for (int kk = 0; kk < 5; ++kk) {
            float4 lo = *(const float4*)(qrow + 32 * kk + 4 * g);
            float4 hi = *(const float4*)(qrow + 32 * kk + 4 * g + 16);
            ss += lo.x*lo.x + lo.y*lo.y + lo.z*lo.z + lo.w*lo.w
                + hi.x*hi.x + hi.y*hi.y + hi.z*hi.z + hi.w*hi.w;
            bf8 f;
            f[0]=(__bf16)(SQSCALE*lo.x); f[1]=(__bf16)(SQSCALE*lo.y);
            f[2]=(__bf16)(SQSCALE*lo.z); f[3]=(__bf16)(SQSCALE*lo.w);
            f[4]=(__bf16)(SQSCALE*hi.x); f[5]=(__bf16)(SQSCALE*hi.y);
            f[6]=(__bf16)(SQSCALE*hi.z); f[7]=(__bf16)(SQSCALE*hi.w);
            qfrag[qf][kk] = f;
        }
        ss += __shfl_xor(ss, 16, 64);
        ss += __shfl_xor(ss, 32, 64);
        const float x2C  = ss * C2SCALE;
        const float x2hi = (float)(__bf16)x2C;
        const float x2lo = x2C - x2hi;
        bf8 z = {(__bf16)0.f,(__bf16)0.f,(__bf16)0.f,(__bf16)0.f,
                 (__bf16)0.f,(__bf16)0.f,(__bf16)0.f,(__bf16)0.f};
        if (g == 0) { z[0] = (__bf16)1.0f; z[1] = (__bf16)1.0f;
                      z[2] = (__bf16)x2hi; z[3] = (__bf16)x2lo; }
        qfrag[qf][5] = z;
    }

    f32x4 acc[2];
    acc[0] = (f32x4){0.f,0.f,0.f,0.f};
    acc[1] = (f32x4){0.f,0.f,0.f,0.f};

    const int ts = (split * ntt) / S;
    const int nt = ((split + 1) * ntt) / S - ts;
    const __bf16* src = pk + (size_t)ts * TILE_E;

    // ---- prologue: stage tile 0 (4 outstanding VMEM instrs per wave)
    stage4(src, &kbuf[0][0], t, wave, lane);

    int idx = 0;   // k % 3
    for (int k = 0; k < nt; ++k) {
        const int nidx = (idx == 2) ? 0 : idx + 1;
        if (k + 1 < nt) {
            stage4(src + (size_t)(k + 1) * TILE_E, &kbuf[nidx][0], t, wave, lane);
            asm volatile("s_waitcnt vmcnt(4)" ::: "memory");   // tile k landed
        } else {
            asm volatile("s_waitcnt vmcnt(0)" ::: "memory");
        }
        __builtin_amdgcn_s_barrier();

        const __bf16* kb = &kbuf[idx][0];
        bf8 mf = *(const bf8*)(kb + 6144 + lane * 8);
        bf8 kf[2][KKN];
        #pragma unroll
        for (int m = 0; m < 2; ++m)
            #pragma unroll
            for (int kk = 0; kk < KKN; ++kk)
                kf[m][kk] = *(const bf8*)(kb + m * (KKN * 512) + kk * 512 + lane * 8);

        // ---- QK^T: 4 interleaved MFMA chains, 6 chunks (incl. norm chunk)
        __builtin_amdgcn_s_setprio(1);
        f32x4 s00 = {0.f,0.f,0.f,0.f}, s01 = {0.f,0.f,0.f,0.f};
        f32x4 s10 = {0.f,0.f,0.f,0.f}, s11 = {0.f,0.f,0.f,0.f};
        #pragma unroll
        for (int kk = 0; kk < KKN; ++kk) {
            s00 = __builtin_amdgcn_mfma_f32_16x16x32_bf16(kf[0][kk], qfrag[0][kk], s00, 0,0,0);
            s01 = __builtin_amdgcn_mfma_f32_16x16x32_bf16(kf[1][kk], qfrag[0][kk], s01, 0,0,0);
            s10 = __builtin_amdgcn_mfma_f32_16x16x32_bf16(kf[0][kk], qfrag[1][kk], s10, 0,0,0);
            s11 = __builtin_amdgcn_mfma_f32_16x16x32_bf16(kf[1][kk], qfrag[1][kk], s11, 0,0,0);
        }
        __builtin_amdgcn_s_setprio(0);

        // ---- s IS C2*d^2: weight = exp2(-sqrt(s)); pack; PV
        bf8 p0, p1;
        #pragma unroll
        for (int r = 0; r < 4; ++r) {
            p0[r]     = (__bf16)__builtin_amdgcn_exp2f(-__builtin_amdgcn_sqrtf(s00[r]));
            p0[4 + r] = (__bf16)__builtin_amdgcn_exp2f(-__builtin_amdgcn_sqrtf(s01[r]));
            p1[r]     = (__bf16)__builtin_amdgcn_exp2f(-__builtin_amdgcn_sqrtf(s10[r]));
            p1[4 + r] = (__bf16)__builtin_amdgcn_exp2f(-__builtin_amdgcn_sqrtf(s11[r]));
        }
        acc[0] = __builtin_amdgcn_mfma_f32_16x16x32_bf16(mf, p0, acc[0], 0,0,0);
        acc[1] = __builtin_amdgcn_mfma_f32_16x16x32_bf16(mf, p1, acc[1], 0,0,0);

        idx = nidx;
    }

    // ---- epilogue: partials [S][N][12] (cols 0..9 = num, col 10 = denom)
    #pragma unroll
    for (int qf = 0; qf < 2; ++qf) {
        if (g < 3) {
            const int q = qbase + qf * 16 + l15;
            *(f32x4*)(part + ((size_t)split * N + q) * 12 + 4 * g) = acc[qf];
        }
    }
}

// 4 threads per query, shfl-reduce, lane0-of-4 writes.
__global__ void combine_kernel(const float* __restrict__ ws, float* __restrict__ out,
                               int N, int nsplit)
{
    int gid = blockIdx.x * blockDim.x + threadIdx.x;
    int q = gid >> 2, part = gid & 3;
    if (q >= N) return;
    f32x4 n0 = {0.f,0.f,0.f,0.f}, n1 = {0.f,0.f,0.f,0.f}, n2 = {0.f,0.f,0.f,0.f};
    for (int s = part; s < nsplit; s += 4) {
        const float* p = ws + ((size_t)s * N + q) * 12;
        n0 += *(const f32x4*)(p);
        n1 += *(const f32x4*)(p + 4);
        n2 += *(const f32x4*)(p + 8);
    }
    #pragma unroll
    for (int d = 1; d < 4; d <<= 1) {
        #pragma unroll
        for (int i = 0; i < 4; ++i) {
            n0[i] += __shfl_xor(n0[i], d, 64);
            n1[i] += __shfl_xor(n1[i], d, 64);
            n2[i] += __shfl_xor(n2[i], d, 64);
        }
    }
    if (part == 0) {
        float inv = 1.f / n2[2];
        float o[NC] = {n0[0],n0[1],n0[2],n0[3],n1[0],n1[1],n1[2],n1[3],n2[0],n2[1]};
        #pragma unroll
        for (int c = 0; c < NC; ++c) out[(size_t)q * NC + c] = o[c] * inv;
    }
}

// ===========================================================================
// FALLBACK (round-1 kernel): used only if ws too small for the packed path.
// ===========================================================================
#define QB 64
#define KVB 128
#define KPAD 164
#define MPAD 18
#define FWSCALE (-1.4426950408889634f / 1.1f)

__global__ __launch_bounds__(256, 2)
void fused_dist_softmin(const float* __restrict__ inp,
                        const float* __restrict__ addr,
                        const float* __restrict__ Mm,
                        float* __restrict__ ws,
                        float* __restrict__ outp,
                        int N, int nsplit, int a_per_split, int direct)
{
    __shared__ __align__(16) __bf16 Klds[KVB][KPAD];
    __shared__ __align__(16) __bf16 Mlds[KVB][MPAD];
    __shared__ float y2lds[KVB];
    __shared__ float x2lds[QB];
    __shared__ float redbuf[4][4][16][16];

    const int bid = blockIdx.x;
    int split, qblock;
    if (nsplit == 8) { split = bid & 7; qblock = bid >> 3; }
    else             { split = bid % nsplit; qblock = bid / nsplit; }

    const int t    = threadIdx.x;
    const int lane = t & 63;
    const int wave = t >> 6;
    const int l15  = lane & 15;
    const int g    = lane >> 4;
    const int foff = 4 * g;

    if (t < QB) {
        const float* row = inp + (size_t)(qblock * QB + t) * NF;
        float s = 0.f;
        #pragma unroll
        for (int i = 0; i < NF/4; ++i) {
            float4 v = *(const float4*)(row + 4*i);
            s += v.x*v.x + v.y*v.y + v.z*v.z + v.w*v.w;
        }
        x2lds[t] = s;
    }

    bf8 qfrag[4][5];
    #pragma unroll
    for (int qf = 0; qf < 4; ++qf) {
        const float* qrow = inp + (size_t)(qblock*QB + qf*16 + l15) * NF;
        #pragma unroll
        for (int kk = 0; kk < 5; ++kk) {
            float4 lo = *(const float4*)(qrow + 32*kk + foff);
            float4 hi = *(const float4*)(qrow + 32*kk + foff + 16);
            bf8 f;
            f[0]=(__bf16)lo.x; f[1]=(__bf16)lo.y; f[2]=(__bf16)lo.z; f[3]=(__bf16)lo.w;
            f[4]=(__bf16)hi.x; f[5]=(__bf16)hi.y; f[6]=(__bf16)hi.z; f[7]=(__bf16)hi.w;
            qfrag[qf][kk] = f;
        }
    }

    __syncthreads();
    float x2q[4];
    #pragma unroll
    for (int qf = 0; qf < 4; ++qf) x2q[qf] = x2lds[qf*16 + l15];

    f32x4 acc[4];
    #pragma unroll
    for (int qf = 0; qf < 4; ++qf) acc[qf] = (f32x4){0.f,0.f,0.f,0.f};

    const int wa      = wave * 32;
    const int a_begin = split * a_per_split;
    const int ntiles  = a_per_split / KVB;

    for (int tile = 0; tile < ntiles; ++tile) {
        const int a0 = a_begin + tile * KVB;
        __syncthreads();
        {
            const int r = t >> 1, h = t & 1;
            const float* rowp = addr + (size_t)(a0 + r) * NF + h*80;
            float ss = 0.f;
            #pragma unroll
            for (int i = 0; i < 20; ++i) {
                float4 v = *(const float4*)(rowp + 4*i);
                ss += v.x*v.x + v.y*v.y + v.z*v.z + v.w*v.w;
                union { __bf16 b[4]; uint2 u; } pk2;
                pk2.b[0]=(__bf16)v.x; pk2.b[1]=(__bf16)v.y;
                pk2.b[2]=(__bf16)v.z; pk2.b[3]=(__bf16)v.w;
                *(uint2*)&Klds[r][h*80 + 4*i] = pk2.u;
            }
            ss += __shfl_xor(ss, 1, 64);
            if (h == 0) y2lds[r] = ss;
        }
        for (int j = t; j < KVB*NC; j += 256) {
            int r = j / NC, c = j % NC;
            Mlds[r][c] = (__bf16)Mm[(size_t)(a0 + r)*NC + c];
        }
        for (int j = t; j < KVB*8; j += 256) {
            int r = j >> 3, c = 10 + (j & 7);
            Mlds[r][c] = (c == 10) ? (__bf16)1.0f : (__bf16)0.0f;
        }
        __syncthreads();

        bf8 kfrag[2][5];
        #pragma unroll
        for (int m = 0; m < 2; ++m) {
            const __bf16* krow = &Klds[wa + 16*m + l15][0];
            #pragma unroll
            for (int kk = 0; kk < 5; ++kk) {
                uint2 lo = *(const uint2*)(krow + 32*kk + foff);
                uint2 hi = *(const uint2*)(krow + 32*kk + foff + 16);
                union { unsigned int u[4]; bf8 v; } fr;
                fr.u[0]=lo.x; fr.u[1]=lo.y; fr.u[2]=hi.x; fr.u[3]=hi.y;
                kfrag[m][kk] = fr.v;
            }
        }
        float y2r[8];
        #pragma unroll
        for (int m = 0; m < 2; ++m)
            #pragma unroll
            for (int r = 0; r < 4; ++r)
                y2r[m*4 + r] = y2lds[wa + 16*m + 4*g + r];

        bf8 mfrag;
        #pragma unroll
        for (int e = 0; e < 8; ++e)
            mfrag[e] = Mlds[wa + 4*g + (e & 3) + 16*(e >> 2)][l15];

        #pragma unroll
        for (int qf = 0; qf < 4; ++qf) {
            f32x4 s0 = {0.f,0.f,0.f,0.f}, s1 = {0.f,0.f,0.f,0.f};
            #pragma unroll
            for (int kk = 0; kk < 5; ++kk) {
                s0 = __builtin_amdgcn_mfma_f32_16x16x32_bf16(kfrag[0][kk], qfrag[qf][kk], s0, 0, 0, 0);
                s1 = __builtin_amdgcn_mfma_f32_16x16x32_bf16(kfrag[1][kk], qfrag[qf][kk], s1, 0, 0, 0);
            }
            bf8 p;
            const float xq = x2q[qf];
            #pragma unroll
            for (int r = 0; r < 4; ++r) {
                float d2a = xq + y2r[r]     - 2.f*s0[r];
                float d2b = xq + y2r[4 + r] - 2.f*s1[r];
                float da = __builtin_amdgcn_sqrtf(d2a);
                float db = __builtin_amdgcn_sqrtf(d2b);
                p[r]     = (__bf16)__builtin_amdgcn_exp2f(da * FWSCALE);
                p[4 + r] = (__bf16)__builtin_amdgcn_exp2f(db * FWSCALE);
            }
            acc[qf] = __builtin_amdgcn_mfma_f32_16x16x32_bf16(mfrag, p, acc[qf], 0, 0, 0);
        }
    }

    #pragma unroll
    for (int qf = 0; qf < 4; ++qf)
        #pragma unroll
        for (int r = 0; r < 4; ++r)
            redbuf[wave][qf][4*g + r][l15] = acc[qf][r];
    __syncthreads();

    const int qf2 = t >> 6;
    const int qq  = (t >> 2) & 15;
    const int cg  = t & 3;
    float v[4];
    #pragma unroll
    for (int i = 0; i < 4; ++i) {
        const int c = cg*4 + i;
        v[i] = redbuf[0][qf2][c][qq] + redbuf[1][qf2][c][qq]
             + redbuf[2][qf2][c][qq] + redbuf[3][qf2][c][qq];
    }
    const int qg = qblock*QB + qf2*16 + qq;
    if (!direct) {
        float4 o; o.x=v[0]; o.y=v[1]; o.z=v[2]; o.w=v[3];
        *(float4*)(ws + ((size_t)split * N + qg) * 16 + cg*4) = o;
    } else {
        float den = redbuf[0][qf2][10][qq] + redbuf[1][qf2][10][qq]
                  + redbuf[2][qf2][10][qq] + redbuf[3][qf2][10][qq];
        float inv = 1.f / den;
        #pragma unroll
        for (int i = 0; i < 4; ++i) {
            int c = cg*4 + i;
            if (c < NC) outp[(size_t)qg * NC + c] = v[i] * inv;
        }
    }
}

__global__ void combine16_kernel(const float* __restrict__ ws, float* __restrict__ out,
                                 int N, int nsplit)
{
    int q = blockIdx.x * blockDim.x + threadIdx.x;
    if (q >= N) return;
    float num[NC];
    #pragma unroll
    for (int c = 0; c < NC; ++c) num[c] = 0.f;
    float den = 0.f;
    for (int s = 0; s < nsplit; ++s) {
        const float* p = ws + ((size_t)s * N + q) * 16;
        #pragma unroll
        for (int c = 0; c < NC; ++c) num[c] += p[c];
        den += p[10];
    }
    float inv = 1.f / den;
    #pragma unroll
    for (int c = 0; c < NC; ++c) out[(size_t)q * NC + c] = num[c] * inv;
}

// ===========================================================================
extern "C" void kernel_launch(void* const* d_in, const int* in_sizes, int n_in,
                              void* d_out, int out_size, void* d_ws, size_t ws_size,
                              hipStream_t stream)
{
    const float* inp  = (const float*)d_in[0];
    const float* addr = (const float*)d_in[1];
    const float* Mm   = (const float*)d_in[2];
    float* out = (float*)d_out;

    const int N = in_sizes[0] / NF;   // 4096
    const int A = in_sizes[1] / NF;   // 32768

    const size_t packed = (size_t)(A / 32) * TILE_B;

    int S = 0;
    const int cand[4] = {32, 16, 8, 4};
    for (int i = 0; i < 4; ++i) {
        int s = cand[i];
        if (packed + (size_t)s * N * 48 <= ws_size) { S = s; break; }
    }

    if (S && (N % 128) == 0 && (A % 128) == 0) {
        char* wsb = (char*)d_ws;
        __bf16* pk  = (__bf16*)wsb;
        float*  prt = (float*)(wsb + packed);

        const int nkb = A / 64, nmb = A / 128;
        pack_kernel<<<dim3(nkb + nmb), 256, 0, stream>>>(addr, Mm, pk, A);

        const int ntt = A / 32;
        fused_fast<<<dim3((N / 128) * S), 256, 0, stream>>>(inp, pk, prt, N, S, ntt);
        combine_kernel<<<dim3((N * 4 + 255) / 256), 256, 0, stream>>>(prt, out, N, S);
    } else {
        float* ws = (float*)d_ws;
        int nsplit = 1;
        for (int s = 8; s >= 2; s >>= 1) {
            if ((size_t)s * N * 16 * sizeof(float) <= ws_size && (A % (s * KVB)) == 0) {
                nsplit = s; break;
            }
        }
        const int direct = (nsplit == 1);
        const int a_per_split = A / nsplit;
        dim3 grid((N / QB) * nsplit);
        fused_dist_softmin<<<grid, 256, 0, stream>>>(inp, addr, Mm, ws, out,
                                                     N, nsplit, a_per_split, direct);
        if (!direct)
            combine16_kernel<<<dim3((N + 255) / 256), 256, 0, stream>>>(ws, out, N, nsplit);
    }
}

// Round 12
// 70.794 us; speedup vs baseline: 1.2422x; 1.0481x over previous
//
#include <hip/hip_runtime.h>
#include <hip/hip_bf16.h>

typedef __bf16 bf8 __attribute__((ext_vector_type(8)));
typedef float f32x4 __attribute__((ext_vector_type(4)));

#define NF 160
#define NC 10
// w = exp(-d/1.1) = exp2(-sqrt(C2*d^2)); C2 = (log2e/1.1)^2.
// QK^T MFMA computes C2*d^2 directly: K feats scaled by -SQ, Q feats by +SQ
// (SQ = sqrt(2*C2)), plus ext features carrying x2*C2, y2*C2 (hi/lo split).
#define WSCALE (1.4426950408889634f / 1.1f)
#define C2SCALE (WSCALE * WSCALE)
#define SQSCALE 1.85483319237f   // sqrt(2*C2)

#define KKN 6                    // feature chunks of 32 (160 data + 4 ext + pad)
// K tile: 32 addr rows, 13312 B:
//   [    0, 6144): K frags [half(2)][kk(6)][lane(64)][8 bf16]
//   [ 6144, 6656): M frags [lane(64)][8 bf16] (PV A-operand, ones col 10)
#define TILE_E 6656   // bf16 elements
#define TILE_B 13312  // bytes
// Q pack: per 16-query block: [kk(6)][lane(64)][8 bf16] = 3072 elems (6144 B)
#define QBLK_E 3072

// ---------------------------------------------------------------------------
__device__ __forceinline__ void gload_lds16(const __bf16* gsrc, __bf16* ldst) {
    __builtin_amdgcn_global_load_lds(
        (const __attribute__((address_space(1))) unsigned int*)gsrc,
        (__attribute__((address_space(3))) unsigned int*)ldst,
        16, 0, 0);
}

// 832 x 16B per tile: 3 full rounds + 1 round on lanes 0..15 of each wave.
// Every wave issues exactly 4 gload_lds instructions -> uniform vmcnt.
__device__ __forceinline__ void stage4(const __bf16* src, __bf16* dst,
                                       int t, int wave, int lane) {
    gload_lds16(src + (size_t)t * 8,          dst + (size_t)t * 8);
    gload_lds16(src + ((size_t)256 + t) * 8,  dst + ((size_t)256 + t) * 8);
    gload_lds16(src + ((size_t)512 + t) * 8,  dst + ((size_t)512 + t) * 8);
    if (lane < 16) {
        const size_t o = (size_t)768 + wave * 16 + lane;
        gload_lds16(src + o * 8, dst + o * 8);
    }
}

// ===========================================================================
// PRE-PASS: K frags (-SQ, ext [y2hi,y2lo,1,1]); M frags; Q frags (+SQ, ext
// [1,1,x2hi,x2lo]) -- main kernel then does ZERO conversion VALU.
// ===========================================================================
__global__ __launch_bounds__(256)
void pack_kernel(const float* __restrict__ addr, const float* __restrict__ Mm,
                 const float* __restrict__ inp,
                 __bf16* __restrict__ pk, __bf16* __restrict__ wq,
                 int A, int N)
{
    const int nkb = A / 64;
    const int nmb = A / 128;
    const int lane = threadIdx.x & 63;
    const int w    = threadIdx.x >> 6;
    const int l15  = lane & 15;
    const int g    = lane >> 4;
    const int bid  = blockIdx.x;

    if (bid < nkb) {
        const int b = bid * 4 + w;              // 16-row K block
        const int p = b >> 1, h = b & 1;        // tile, half
        const float* row = addr + (size_t)(b * 16 + l15) * NF;
        __bf16* dst = pk + (size_t)p * TILE_E + h * (KKN * 512);
        float ss = 0.f;
        #pragma unroll
        for (int kk = 0; kk < 5; ++kk) {
            float4 lo = *(const float4*)(row + 32 * kk + 4 * g);
            float4 hi = *(const float4*)(row + 32 * kk + 4 * g + 16);
            ss += lo.x*lo.x + lo.y*lo.y + lo.z*lo.z + lo.w*lo.w
                + hi.x*hi.x + hi.y*hi.y + hi.z*hi.z + hi.w*hi.w;
            bf8 f;
            f[0]=(__bf16)(-SQSCALE*lo.x); f[1]=(__bf16)(-SQSCALE*lo.y);
            f[2]=(__bf16)(-SQSCALE*lo.z); f[3]=(__bf16)(-SQSCALE*lo.w);
            f[4]=(__bf16)(-SQSCALE*hi.x); f[5]=(__bf16)(-SQSCALE*hi.y);
            f[6]=(__bf16)(-SQSCALE*hi.z); f[7]=(__bf16)(-SQSCALE*hi.w);
            *(bf8*)(dst + kk * 512 + lane * 8) = f;
        }
        ss += __shfl_xor(ss, 16, 64);
        ss += __shfl_xor(ss, 32, 64);
        const float y2C  = ss * C2SCALE;
        const float y2hi = (float)(__bf16)y2C;
        const float y2lo = y2C - y2hi;
        bf8 z = {(__bf16)0.f,(__bf16)0.f,(__bf16)0.f,(__bf16)0.f,
                 (__bf16)0.f,(__bf16)0.f,(__bf16)0.f,(__bf16)0.f};
        if (g == 0) { z[0] = (__bf16)y2hi; z[1] = (__bf16)y2lo;
                      z[2] = (__bf16)1.0f; z[3] = (__bf16)1.0f; }
        *(bf8*)(dst + 5 * 512 + lane * 8) = z;
    } else if (bid < nkb + nmb) {
        const int mb = (bid - nkb) * 4 + w;     // 32-row tile index
        bf8 f;
        #pragma unroll
        for (int e = 0; e < 8; ++e) {
            int r = mb * 32 + 4 * g + (e & 3) + 16 * (e >> 2);
            float v = (l15 < NC) ? Mm[(size_t)r * NC + l15] : (l15 == NC ? 1.0f : 0.0f);
            f[e] = (__bf16)v;
        }
        *(bf8*)(pk + (size_t)mb * TILE_E + 6144 + lane * 8) = f;
    } else {
        const int qb = (bid - nkb - nmb) * 4 + w;   // 16-query block
        const float* row = inp + (size_t)(qb * 16 + l15) * NF;
        __bf16* dst = wq + (size_t)qb * QBLK_E;
        float ss = 0.f;
        #pragma unroll
        for (int kk = 0; kk < 5; ++kk) {
            float4 lo = *(const float4*)(row + 32 * kk + 4 * g);
            float4 hi = *(const float4*)(row + 32 * kk + 4 * g + 16);
            ss += lo.x*lo.x + lo.y*lo.y + lo.z*lo.z + lo.w*lo.w
                + hi.x*hi.x + hi.y*hi.y + hi.z*hi.z + hi.w*hi.w;
            bf8 f;
            f[0]=(__bf16)(SQSCALE*lo.x); f[1]=(__bf16)(SQSCALE*lo.y);
            f[2]=(__bf16)(SQSCALE*lo.z); f[3]=(__bf16)(SQSCALE*lo.w);
            f[4]=(__bf16)(SQSCALE*hi.x); f[5]=(__bf16)(SQSCALE*hi.y);
            f[6]=(__bf16)(SQSCALE*hi.z); f[7]=(__bf16)(SQSCALE*hi.w);
            *(bf8*)(dst + kk * 512 + lane * 8) = f;
        }
        ss += __shfl_xor(ss, 16, 64);
        ss += __shfl_xor(ss, 32, 64);
        const float x2C  = ss * C2SCALE;
        const float x2hi = (float)(__bf16)x2C;
        const float x2lo = x2C - x2hi;
        bf8 z = {(__bf16)0.f,(__bf16)0.f,(__bf16)0.f,(__bf16)0.f,
                 (__bf16)0.f,(__bf16)0.f,(__bf16)0.f,(__bf16)0.f};
        if (g == 0) { z[0] = (__bf16)1.0f; z[1] = (__bf16)1.0f;
                      z[2] = (__bf16)x2hi; z[3] = (__bf16)x2lo; }
        *(bf8*)(dst + 5 * 512 + lane * 8) = z;
    }
}

// ===========================================================================
// MAIN: R11 pipeline (3 LDS buffers, counted vmcnt(4), one bare barrier/tile)
// + prepacked Q (prologue = 12 coalesced loads, no VALU) + wave-parity
// stagger (odd waves process the two 16-row halves in reverse order, so one
// wave's MFMA burst overlaps a neighbor wave's trans burst).
// ===========================================================================
__global__ void fused_fast(const __bf16* __restrict__ wq,
                           const __bf16* __restrict__ pk,
                           float* __restrict__ part,
                           int N, int S, int ntt)
{
    __shared__ __align__(16) __bf16 kbuf[3][TILE_E];   // 39,936 B

    const int bid   = blockIdx.x;
    const int split = bid % S;
    const int qblk  = bid / S;
    const int t     = threadIdx.x;
    const int lane  = t & 63;
    const int wave  = t >> 6;
    const int l15   = lane & 15;
    const int g     = lane >> 4;

    // ---- prologue: load prepacked Q fragments (pure loads, no conversion)
    const int qbase = qblk * 128 + wave * 32;
    const __bf16* wqp = wq + (size_t)(qbase >> 4) * QBLK_E;
    bf8 qfrag[2][KKN];
    #pragma unroll
    for (int qf = 0; qf < 2; ++qf)
        #pragma unroll
        for (int kk = 0; kk < KKN; ++kk)
            qfrag[qf][kk] = *(const bf8*)(wqp + (size_t)qf * QBLK_E + kk * 512 + lane * 8);

    f32x4 acc[2];
    acc[0] = (f32x4){0.f,0.f,0.f,0.f};
    acc[1] = (f32x4){0.f,0.f,0.f,0.f};

    const int ts = (split * ntt) / S;
    const int nt = ((split + 1) * ntt) / S - ts;
    const __bf16* src = pk + (size_t)ts * TILE_E;

    // ---- stage tile 0
    stage4(src, &kbuf[0][0], t, wave, lane);

#define QK_HALF(MH)                                                            \
    {                                                                          \
        bf8 kf[KKN];                                                           \
        _Pragma("unroll")                                                      \
        for (int kk = 0; kk < KKN; ++kk)                                       \
            kf[kk] = *(const bf8*)(kb + (MH) * (KKN*512) + kk * 512 + lane*8); \
        __builtin_amdgcn_s_setprio(1);                                         \
        f32x4 a0 = {0.f,0.f,0.f,0.f}, a1 = {0.f,0.f,0.f,0.f};                  \
        _Pragma("unroll")                                                      \
        for (int kk = 0; kk < KKN; ++kk) {                                     \
            a0 = __builtin_amdgcn_mfma_f32_16x16x32_bf16(kf[kk], qfrag[0][kk], a0, 0,0,0); \
            a1 = __builtin_amdgcn_mfma_f32_16x16x32_bf16(kf[kk], qfrag[1][kk], a1, 0,0,0); \
        }                                                                      \
        __builtin_amdgcn_s_setprio(0);                                         \
        _Pragma("unroll")                                                      \
        for (int r = 0; r < 4; ++r) {                                          \
            p0[(MH)*4 + r] = (__bf16)__builtin_amdgcn_exp2f(-__builtin_amdgcn_sqrtf(a0[r])); \
            p1[(MH)*4 + r] = (__bf16)__builtin_amdgcn_exp2f(-__builtin_amdgcn_sqrtf(a1[r])); \
        }                                                                      \
    }

    int idx = 0;   // k % 3
    for (int k = 0; k < nt; ++k) {
        const int nidx = (idx == 2) ? 0 : idx + 1;
        if (k + 1 < nt) {
            stage4(src + (size_t)(k + 1) * TILE_E, &kbuf[nidx][0], t, wave, lane);
            asm volatile("s_waitcnt vmcnt(4)" ::: "memory");   // tile k landed
        } else {
            asm volatile("s_waitcnt vmcnt(0)" ::: "memory");
        }
        __builtin_amdgcn_s_barrier();

        const __bf16* kb = &kbuf[idx][0];
        bf8 mf = *(const bf8*)(kb + 6144 + lane * 8);

        bf8 p0, p1;
        if ((wave & 1) == 0) { QK_HALF(0); QK_HALF(1); }
        else                 { QK_HALF(1); QK_HALF(0); }

        acc[0] = __builtin_amdgcn_mfma_f32_16x16x32_bf16(mf, p0, acc[0], 0,0,0);
        acc[1] = __builtin_amdgcn_mfma_f32_16x16x32_bf16(mf, p1, acc[1], 0,0,0);

        idx = nidx;
    }
#undef QK_HALF

    // ---- epilogue: partials [S][N][12] (cols 0..9 = num, col 10 = denom)
    #pragma unroll
    for (int qf = 0; qf < 2; ++qf) {
        if (g < 3) {
            const int q = qbase + qf * 16 + l15;
            *(f32x4*)(part + ((size_t)split * N + q) * 12 + 4 * g) = acc[qf];
        }
    }
}

// 4 threads per query, shfl-reduce, lane0-of-4 writes.
__global__ void combine_kernel(const float* __restrict__ ws, float* __restrict__ out,
                               int N, int nsplit)
{
    int gid = blockIdx.x * blockDim.x + threadIdx.x;
    int q = gid >> 2, part = gid & 3;
    if (q >= N) return;
    f32x4 n0 = {0.f,0.f,0.f,0.f}, n1 = {0.f,0.f,0.f,0.f}, n2 = {0.f,0.f,0.f,0.f};
    for (int s = part; s < nsplit; s += 4) {
        const float* p = ws + ((size_t)s * N + q) * 12;
        n0 += *(const f32x4*)(p);
        n1 += *(const f32x4*)(p + 4);
        n2 += *(const f32x4*)(p + 8);
    }
    #pragma unroll
    for (int d = 1; d < 4; d <<= 1) {
        #pragma unroll
        for (int i = 0; i < 4; ++i) {
            n0[i] += __shfl_xor(n0[i], d, 64);
            n1[i] += __shfl_xor(n1[i], d, 64);
            n2[i] += __shfl_xor(n2[i], d, 64);
        }
    }
    if (part == 0) {
        float inv = 1.f / n2[2];
        float o[NC] = {n0[0],n0[1],n0[2],n0[3],n1[0],n1[1],n1[2],n1[3],n2[0],n2[1]};
        #pragma unroll
        for (int c = 0; c < NC; ++c) out[(size_t)q * NC + c] = o[c] * inv;
    }
}

// ===========================================================================
// FALLBACK (round-1 kernel): used only if ws too small for the packed path.
// ===========================================================================
#define QB 64
#define KVB 128
#define KPAD 164
#define MPAD 18
#define FWSCALE (-1.4426950408889634f / 1.1f)

__global__ __launch_bounds__(256, 2)
void fused_dist_softmin(const float* __restrict__ inp,
                        const float* __restrict__ addr,
                        const float* __restrict__ Mm,
                        float* __restrict__ ws,
                        float* __restrict__ outp,
                        int N, int nsplit, int a_per_split, int direct)
{
    __shared__ __align__(16) __bf16 Klds[KVB][KPAD];
    __shared__ __align__(16) __bf16 Mlds[KVB][MPAD];
    __shared__ float y2lds[KVB];
    __shared__ float x2lds[QB];
    __shared__ float redbuf[4][4][16][16];

    const int bid = blockIdx.x;
    int split, qblock;
    if (nsplit == 8) { split = bid & 7; qblock = bid >> 3; }
    else             { split = bid % nsplit; qblock = bid / nsplit; }

    const int t    = threadIdx.x;
    const int lane = t & 63;
    const int wave = t >> 6;
    const int l15  = lane & 15;
    const int g    = lane >> 4;
    const int foff = 4 * g;

    if (t < QB) {
        const float* row = inp + (size_t)(qblock * QB + t) * NF;
        float s = 0.f;
        #pragma unroll
        for (int i = 0; i < NF/4; ++i) {
            float4 v = *(const float4*)(row + 4*i);
            s += v.x*v.x + v.y*v.y + v.z*v.z + v.w*v.w;
        }
        x2lds[t] = s;
    }

    bf8 qfrag[4][5];
    #pragma unroll
    for (int qf = 0; qf < 4; ++qf) {
        const float* qrow = inp + (size_t)(qblock*QB + qf*16 + l15) * NF;
        #pragma unroll
        for (int kk = 0; kk < 5; ++kk) {
            float4 lo = *(const float4*)(qrow + 32*kk + foff);
            float4 hi = *(const float4*)(qrow + 32*kk + foff + 16);
            bf8 f;
            f[0]=(__bf16)lo.x; f[1]=(__bf16)lo.y; f[2]=(__bf16)lo.z; f[3]=(__bf16)lo.w;
            f[4]=(__bf16)hi.x; f[5]=(__bf16)hi.y; f[6]=(__bf16)hi.z; f[7]=(__bf16)hi.w;
            qfrag[qf][kk] = f;
        }
    }

    __syncthreads();
    float x2q[4];
    #pragma unroll
    for (int qf = 0; qf < 4; ++qf) x2q[qf] = x2lds[qf*16 + l15];

    f32x4 acc[4];
    #pragma unroll
    for (int qf = 0; qf < 4; ++qf) acc[qf] = (f32x4){0.f,0.f,0.f,0.f};

    const int wa      = wave * 32;
    const int a_begin = split * a_per_split;
    const int ntiles  = a_per_split / KVB;

    for (int tile = 0; tile < ntiles; ++tile) {
        const int a0 = a_begin + tile * KVB;
        __syncthreads();
        {
            const int r = t >> 1, h = t & 1;
            const float* rowp = addr + (size_t)(a0 + r) * NF + h*80;
            float ss = 0.f;
            #pragma unroll
            for (int i = 0; i < 20; ++i) {
                float4 v = *(const float4*)(rowp + 4*i);
                ss += v.x*v.x + v.y*v.y + v.z*v.z + v.w*v.w;
                union { __bf16 b[4]; uint2 u; } pk2;
                pk2.b[0]=(__bf16)v.x; pk2.b[1]=(__bf16)v.y;
                pk2.b[2]=(__bf16)v.z; pk2.b[3]=(__bf16)v.w;
                *(uint2*)&Klds[r][h*80 + 4*i] = pk2.u;
            }
            ss += __shfl_xor(ss, 1, 64);
            if (h == 0) y2lds[r] = ss;
        }
        for (int j = t; j < KVB*NC; j += 256) {
            int r = j / NC, c = j % NC;
            Mlds[r][c] = (__bf16)Mm[(size_t)(a0 + r)*NC + c];
        }
        for (int j = t; j < KVB*8; j += 256) {
            int r = j >> 3, c = 10 + (j & 7);
            Mlds[r][c] = (c == 10) ? (__bf16)1.0f : (__bf16)0.0f;
        }
        __syncthreads();

        bf8 kfrag[2][5];
        #pragma unroll
        for (int m = 0; m < 2; ++m) {
            const __bf16* krow = &Klds[wa + 16*m + l15][0];
            #pragma unroll
            for (int kk = 0; kk < 5; ++kk) {
                uint2 lo = *(const uint2*)(krow + 32*kk + foff);
                uint2 hi = *(const uint2*)(krow + 32*kk + foff + 16);
                union { unsigned int u[4]; bf8 v; } fr;
                fr.u[0]=lo.x; fr.u[1]=lo.y; fr.u[2]=hi.x; fr.u[3]=hi.y;
                kfrag[m][kk] = fr.v;
            }
        }
        float y2r[8];
        #pragma unroll
        for (int m = 0; m < 2; ++m)
            #pragma unroll
            for (int r = 0; r < 4; ++r)
                y2r[m*4 + r] = y2lds[wa + 16*m + 4*g + r];

        bf8 mfrag;
        #pragma unroll
        for (int e = 0; e < 8; ++e)
            mfrag[e] = Mlds[wa + 4*g + (e & 3) + 16*(e >> 2)][l15];

        #pragma unroll
        for (int qf = 0; qf < 4; ++qf) {
            f32x4 s0 = {0.f,0.f,0.f,0.f}, s1 = {0.f,0.f,0.f,0.f};
            #pragma unroll
            for (int kk = 0; kk < 5; ++kk) {
                s0 = __builtin_amdgcn_mfma_f32_16x16x32_bf16(kfrag[0][kk], qfrag[qf][kk], s0, 0, 0, 0);
                s1 = __builtin_amdgcn_mfma_f32_16x16x32_bf16(kfrag[1][kk], qfrag[qf][kk], s1, 0, 0, 0);
            }
            bf8 p;
            const float xq = x2q[qf];
            #pragma unroll
            for (int r = 0; r < 4; ++r) {
                float d2a = xq + y2r[r]     - 2.f*s0[r];
                float d2b = xq + y2r[4 + r] - 2.f*s1[r];
                float da = __builtin_amdgcn_sqrtf(d2a);
                float db = __builtin_amdgcn_sqrtf(d2b);
                p[r]     = (__bf16)__builtin_amdgcn_exp2f(da * FWSCALE);
                p[4 + r] = (__bf16)__builtin_amdgcn_exp2f(db * FWSCALE);
            }
            acc[qf] = __builtin_amdgcn_mfma_f32_16x16x32_bf16(mfrag, p, acc[qf], 0, 0, 0);
        }
    }

    #pragma unroll
    for (int qf = 0; qf < 4; ++qf)
        #pragma unroll
        for (int r = 0; r < 4; ++r)
            redbuf[wave][qf][4*g + r][l15] = acc[qf][r];
    __syncthreads();

    const int qf2 = t >> 6;
    const int qq  = (t >> 2) & 15;
    const int cg  = t & 3;
    float v[4];
    #pragma unroll
    for (int i = 0; i < 4; ++i) {
        const int c = cg*4 + i;
        v[i] = redbuf[0][qf2][c][qq] + redbuf[1][qf2][c][qq]
             + redbuf[2][qf2][c][qq] + redbuf[3][qf2][c][qq];
    }
    const int qg = qblock*QB + qf2*16 + qq;
    if (!direct) {
        float4 o; o.x=v[0]; o.y=v[1]; o.z=v[2]; o.w=v[3];
        *(float4*)(ws + ((size_t)split * N + qg) * 16 + cg*4) = o;
    } else {
        float den = redbuf[0][qf2][10][qq] + redbuf[1][qf2][10][qq]
                  + redbuf[2][qf2][10][qq] + redbuf[3][qf2][10][qq];
        float inv = 1.f / den;
        #pragma unroll
        for (int i = 0; i < 4; ++i) {
            int c = cg*4 + i;
            if (c < NC) outp[(size_t)qg * NC + c] = v[i] * inv;
        }
    }
}

__global__ void combine16_kernel(const float* __restrict__ ws, float* __restrict__ out,
                                 int N, int nsplit)
{
    int q = blockIdx.x * blockDim.x + threadIdx.x;
    if (q >= N) return;
    float num[NC];
    #pragma unroll
    for (int c = 0; c < NC; ++c) num[c] = 0.f;
    float den = 0.f;
    for (int s = 0; s < nsplit; ++s) {
        const float* p = ws + ((size_t)s * N + q) * 16;
        #pragma unroll
        for (int c = 0; c < NC; ++c) num[c] += p[c];
        den += p[10];
    }
    float inv = 1.f / den;
    #pragma unroll
    for (int c = 0; c < NC; ++c) out[(size_t)q * NC + c] = num[c] * inv;
}

// ===========================================================================
extern "C" void kernel_launch(void* const* d_in, const int* in_sizes, int n_in,
                              void* d_out, int out_size, void* d_ws, size_t ws_size,
                              hipStream_t stream)
{
    const float* inp  = (const float*)d_in[0];
    const float* addr = (const float*)d_in[1];
    const float* Mm   = (const float*)d_in[2];
    float* out = (float*)d_out;

    const int N = in_sizes[0] / NF;   // 4096
    const int A = in_sizes[1] / NF;   // 32768

    const size_t kA = (size_t)(A / 32) * TILE_B;       // packed K+M tiles
    const size_t qA = (size_t)(N / 16) * QBLK_E * 2;   // packed Q (bytes)
    const size_t packed = kA + qA;

    int S = 0;
    const int cand[4] = {32, 16, 8, 4};
    for (int i = 0; i < 4; ++i) {
        int s = cand[i];
        if (packed + (size_t)s * N * 48 <= ws_size) { S = s; break; }
    }

    if (S && (N % 128) == 0 && (A % 128) == 0) {
        char* wsb = (char*)d_ws;
        __bf16* pk  = (__bf16*)wsb;
        __bf16* wq  = (__bf16*)(wsb + kA);
        float*  prt = (float*)(wsb + packed);

        const int nkb = A / 64, nmb = A / 128, nqb = N / 64;
        pack_kernel<<<dim3(nkb + nmb + nqb), 256, 0, stream>>>(addr, Mm, inp, pk, wq, A, N);

        const int ntt = A / 32;
        fused_fast<<<dim3((N / 128) * S), 256, 0, stream>>>(wq, pk, prt, N, S, ntt);
        combine_kernel<<<dim3((N * 4 + 255) / 256), 256, 0, stream>>>(prt, out, N, S);
    } else {
        float* ws = (float*)d_ws;
        int nsplit = 1;
        for (int s = 8; s >= 2; s >>= 1) {
            if ((size_t)s * N * 16 * sizeof(float) <= ws_size && (A % (s * KVB)) == 0) {
                nsplit = s; break;
            }
        }
        const int direct = (nsplit == 1);
        const int a_per_split = A / nsplit;
        dim3 grid((N / QB) * nsplit);
        fused_dist_softmin<<<grid, 256, 0, stream>>>(inp, addr, Mm, ws, out,
                                                     N, nsplit, a_per_split, direct);
        if (!direct)
            combine16_kernel<<<dim3((N + 255) / 256), 256, 0, stream>>>(ws, out, N, nsplit);
    }
}